// Round 1
// baseline (923.839 us; speedup 1.0000x reference)
//
#include <hip/hip_runtime.h>
#include <math.h>

#define Hh 192
#define Ww 192
#define HWc 36864
#define Bc 4
#define NWc 576
#define NKc 288
#define WNc 24

// ---------------- K1: q/k/v 1x1 convs (48 -> 3x64) ----------------
__global__ __launch_bounds__(256) void k_qkv(const float* __restrict__ x,
    const float* __restrict__ wq, const float* __restrict__ bq,
    const float* __restrict__ wk, const float* __restrict__ bk,
    const float* __restrict__ wv, const float* __restrict__ bv,
    float* __restrict__ q, float* __restrict__ k, float* __restrict__ v)
{
    int g = blockIdx.x * 256 + threadIdx.x;
    int b = g / HWc, rem = g % HWc;
    float xr[48];
    const float* xp = x + (size_t)b * 48 * HWc + rem;
    #pragma unroll
    for (int c = 0; c < 48; ++c) xr[c] = xp[(size_t)c * HWc];

    float* qp = q + (size_t)b * 64 * HWc + rem;
    for (int oc = 0; oc < 64; ++oc) {
        float a = bq[oc];
        const float* wr = wq + oc * 48;
        #pragma unroll
        for (int c = 0; c < 48; ++c) a = fmaf(xr[c], wr[c], a);
        qp[(size_t)oc * HWc] = a;
    }
    float* kp = k + (size_t)b * 64 * HWc + rem;
    for (int oc = 0; oc < 64; ++oc) {
        float a = bk[oc];
        const float* wr = wk + oc * 48;
        #pragma unroll
        for (int c = 0; c < 48; ++c) a = fmaf(xr[c], wr[c], a);
        kp[(size_t)oc * HWc] = a;
    }
    float* vp = v + (size_t)b * 64 * HWc + rem;
    for (int oc = 0; oc < 64; ++oc) {
        float a = bv[oc];
        const float* wr = wv + oc * 48;
        #pragma unroll
        for (int c = 0; c < 48; ++c) a = fmaf(xr[c], wr[c], a);
        vp[(size_t)oc * HWc] = a;
    }
}

// ------- K2: cond conv (68->17) + LayerNorm + leaky + channel-mean -------
__global__ __launch_bounds__(256) void k_cond(const float* __restrict__ vs,
    const float* __restrict__ cg,
    const float* __restrict__ w_in, const float* __restrict__ b_in,
    const float* __restrict__ ln_w, const float* __restrict__ ln_b,
    float* __restrict__ t, float* __restrict__ mpix)
{
    int g = blockIdx.x * 256 + threadIdx.x;
    int b = g / HWc, rem = g % HWc;
    int y = rem / Ww, xx = rem % Ww;

    float in[68];
    const float* vp = vs + (size_t)b * 64 * HWc + rem;
    #pragma unroll
    for (int c = 0; c < 64; ++c) in[c] = vp[(size_t)c * HWc];
    in[64] = cg[((size_t)b * 2 + 0) * HWc + rem];
    in[65] = cg[((size_t)b * 2 + 1) * HWc + rem];
    const float step = 2.0f / 7.0f;
    in[66] = -1.0f + step * (float)(y & 7);   // gy = lin[row%8]
    in[67] = -1.0f + step * (float)(xx & 7);  // gx = lin[col%8]

    float tv[17];
    float mu = 0.f;
    #pragma unroll
    for (int o = 0; o < 17; ++o) {
        float a = b_in[o];
        const float* wr = w_in + o * 68;
        #pragma unroll
        for (int c = 0; c < 68; ++c) a = fmaf(in[c], wr[c], a);
        tv[o] = a;
        mu += a;
    }
    mu *= (1.f / 17.f);
    float var = 0.f;
    #pragma unroll
    for (int o = 0; o < 17; ++o) { float d = tv[o] - mu; var = fmaf(d, d, var); }
    var *= (1.f / 17.f);
    float rstd = 1.f / sqrtf(var + 1e-6f);

    float msum = 0.f;
    #pragma unroll
    for (int o = 0; o < 17; ++o) {
        float z = (tv[o] - mu) * rstd * ln_w[o] + ln_b[o];
        z = (z >= 0.f) ? z : 0.1f * z;
        t[((size_t)b * 17 + o) * HWc + rem] = z;
        msum += z;
    }
    mpix[(size_t)b * HWc + rem] = msum * (1.f / 17.f);
}

// ---------------- K3: 3x3 conv (17->1) + sigmoid ----------------
__global__ __launch_bounds__(256) void k_sa(const float* __restrict__ t,
    const float* __restrict__ w_sa, const float* __restrict__ b_sa,
    float* __restrict__ sa)
{
    int g = blockIdx.x * 256 + threadIdx.x;
    int b = g / HWc, rem = g % HWc;
    int y = rem / Ww, xx = rem % Ww;

    float a = b_sa[0];
    for (int c = 0; c < 17; ++c) {
        const float* tp = t + ((size_t)b * 17 + c) * HWc;
        const float* wr = w_sa + c * 9;
        #pragma unroll
        for (int ki = 0; ki < 3; ++ki) {
            int yy = y + ki - 1;
            if ((unsigned)yy >= 192u) continue;
            #pragma unroll
            for (int kj = 0; kj < 3; ++kj) {
                int xc = xx + kj - 1;
                if ((unsigned)xc >= 192u) continue;
                a = fmaf(tp[yy * Ww + xc], wr[ki * 3 + kj], a);
            }
        }
    }
    sa[g] = 1.f / (1.f + expf(-a));
}

// -------- K4: window score MLP + stable descending rank -> flag --------
__global__ __launch_bounds__(576) void k_score(const float* __restrict__ mpix,
    const float* __restrict__ w_m1, const float* __restrict__ b_m1,
    const float* __restrict__ w_m2, const float* __restrict__ b_m2,
    int* __restrict__ flag)
{
    __shared__ float sc[NWc];
    int b = blockIdx.x;
    int w = threadIdx.x;
    {
        int hy = w / WNc, wx = w % WNc;
        const float* mp = mpix + (size_t)b * HWc + (hy * 8) * Ww + wx * 8;
        float m[64];
        #pragma unroll
        for (int l = 0; l < 64; ++l) m[l] = mp[(l >> 3) * Ww + (l & 7)];
        float h1[8];
        #pragma unroll
        for (int j = 0; j < 8; ++j) {
            float a = b_m1[j];
            const float* wr = w_m1 + j * 64;
            #pragma unroll
            for (int l = 0; l < 64; ++l) a = fmaf(m[l], wr[l], a);
            h1[j] = (a >= 0.f) ? a : 0.1f * a;
        }
        float l0 = b_m2[0], l1 = b_m2[1];
        #pragma unroll
        for (int j = 0; j < 8; ++j) {
            l0 = fmaf(h1[j], w_m2[j], l0);
            l1 = fmaf(h1[j], w_m2[8 + j], l1);
        }
        float mx = fmaxf(l0, l1);
        float e0 = expf(l0 - mx), e1 = expf(l1 - mx);
        sc[w] = e0 / (e0 + e1);  // softmax[0]
    }
    __syncthreads();
    float s = sc[w];
    int cnt = 0;
    for (int w2 = 0; w2 < NWc; ++w2) {
        float s2 = sc[w2];
        cnt += ((s2 > s) || (s2 == s && w2 < w)) ? 1 : 0;
    }
    flag[b * NWc + w] = (cnt < NKc) ? 1 : 0;
}

// ---- K5: per-window attention OR easy path + fused output 1x1 conv ----
__global__ __launch_bounds__(256) void k_attn(const float* __restrict__ qs,
    const float* __restrict__ ks, const float* __restrict__ vsb,
    const float* __restrict__ sab, const int* __restrict__ flag,
    const float* __restrict__ relh, const float* __restrict__ relw,
    const float* __restrict__ w_out, const float* __restrict__ b_out,
    float* __restrict__ out)
{
    __shared__ float mlds[64][65];     // [pixel][channel], +1 pad
    __shared__ float wlds[48 * 64];    // w_out staged
    int tid = threadIdx.x;
    for (int i = tid; i < 48 * 64; i += 256) wlds[i] = w_out[i];

    int blk = blockIdx.x;
    int b = blk / NWc, n = blk % NWc;
    int hy = n / WNc, wx = n % WNc;
    int y0 = hy * 8, x0 = wx * 8;

    if (flag[b * NWc + n]) {
        int h = tid >> 6, l = tid & 63;        // head (wave-uniform), query pos
        int qr = l >> 3, qc = l & 7;
        const float* qp = qs + ((size_t)(b * 64 + h * 16)) * HWc + (y0 + qr) * Ww + (x0 + qc);
        float qv[16];
        #pragma unroll
        for (int d = 0; d < 16; ++d) qv[d] = qp[(size_t)d * HWc];

        // relative-position logit tables: rel index in [4,22], always valid
        float rw[12], rh[12];
        #pragma unroll
        for (int kc = 0; kc < 12; ++kc) {
            const float* rp = relw + (kc - qc + 11) * 16;
            float a = 0.f;
            #pragma unroll
            for (int d = 0; d < 16; ++d) a = fmaf(qv[d], rp[d], a);
            rw[kc] = a;
        }
        #pragma unroll
        for (int kr = 0; kr < 12; ++kr) {
            const float* rp = relh + (kr - qr + 11) * 16;
            float a = 0.f;
            #pragma unroll
            for (int d = 0; d < 16; ++d) a = fmaf(qv[d], rp[d], a);
            rh[kr] = a;
        }

        const float* kb = ks  + ((size_t)(b * 64 + h * 16)) * HWc;
        const float* vb = vsb + ((size_t)(b * 64 + h * 16)) * HWc;

        // pass A: max
        float mmax = -1e30f;
        #pragma unroll 1
        for (int kr = 0; kr < 12; ++kr) {
            int ky = y0 - 2 + kr;
            bool rok = ((unsigned)ky < 192u);
            #pragma unroll
            for (int kc = 0; kc < 12; ++kc) {
                int kx = x0 - 2 + kc;
                float s = rw[kc] + rh[kr];
                if (rok && ((unsigned)kx < 192u)) {
                    const float* kp = kb + ky * Ww + kx;
                    float dt = 0.f;
                    #pragma unroll
                    for (int d = 0; d < 16; ++d) dt = fmaf(qv[d], kp[(size_t)d * HWc], dt);
                    s = fmaf(0.25f, dt, s);
                }
                mmax = fmaxf(mmax, s);
            }
        }
        // pass B: sum + PV (recompute logits)
        float lsum = 0.f;
        float acc[16];
        #pragma unroll
        for (int d = 0; d < 16; ++d) acc[d] = 0.f;
        #pragma unroll 1
        for (int kr = 0; kr < 12; ++kr) {
            int ky = y0 - 2 + kr;
            bool rok = ((unsigned)ky < 192u);
            #pragma unroll
            for (int kc = 0; kc < 12; ++kc) {
                int kx = x0 - 2 + kc;
                float s = rw[kc] + rh[kr];
                bool inb = rok && ((unsigned)kx < 192u);
                if (inb) {
                    const float* kp = kb + ky * Ww + kx;
                    float dt = 0.f;
                    #pragma unroll
                    for (int d = 0; d < 16; ++d) dt = fmaf(qv[d], kp[(size_t)d * HWc], dt);
                    s = fmaf(0.25f, dt, s);
                }
                float e = expf(s - mmax);
                lsum += e;
                if (inb) {
                    const float* vp = vb + ky * Ww + kx;
                    #pragma unroll
                    for (int d = 0; d < 16; ++d) acc[d] = fmaf(e, vp[(size_t)d * HWc], acc[d]);
                }
            }
        }
        float inv = 1.f / lsum;
        #pragma unroll
        for (int d = 0; d < 16; ++d) mlds[l][h * 16 + d] = acc[d] * inv;
    } else {
        // easy path: vs * sa
        #pragma unroll
        for (int i = 0; i < 16; ++i) {
            int idx = i * 256 + tid;
            int c = idx >> 6, l = idx & 63;
            int gy = y0 + (l >> 3), gx = x0 + (l & 7);
            mlds[l][c] = vsb[((size_t)(b * 64 + c)) * HWc + gy * Ww + gx]
                       * sab[(size_t)b * HWc + gy * Ww + gx];
        }
    }
    __syncthreads();

    // fused output conv: 64 -> 48 per pixel
    {
        int l = tid & 63, og = tid >> 6;
        int gy = y0 + (l >> 3), gx = x0 + (l & 7);
        float mv[64];
        #pragma unroll
        for (int c = 0; c < 64; ++c) mv[c] = mlds[l][c];
        #pragma unroll 1
        for (int j = 0; j < 12; ++j) {
            int oc = og * 12 + j;
            float a = b_out[oc];
            const float* wr = wlds + oc * 64;
            #pragma unroll
            for (int c = 0; c < 64; ++c) a = fmaf(mv[c], wr[c], a);
            out[((size_t)(b * 48 + oc)) * HWc + gy * Ww + gx] = a;
        }
    }
}

extern "C" void kernel_launch(void* const* d_in, const int* in_sizes, int n_in,
                              void* d_out, int out_size, void* d_ws, size_t ws_size,
                              hipStream_t stream)
{
    const float* x    = (const float*)d_in[0];
    const float* cg   = (const float*)d_in[1];
    const float* wq   = (const float*)d_in[2];
    const float* bq   = (const float*)d_in[3];
    const float* wk   = (const float*)d_in[4];
    const float* bk   = (const float*)d_in[5];
    const float* wv   = (const float*)d_in[6];
    const float* bv   = (const float*)d_in[7];
    const float* w_in = (const float*)d_in[8];
    const float* b_in = (const float*)d_in[9];
    const float* ln_w = (const float*)d_in[10];
    const float* ln_b = (const float*)d_in[11];
    const float* w_sa = (const float*)d_in[12];
    const float* b_sa = (const float*)d_in[13];
    const float* w_m1 = (const float*)d_in[14];
    const float* b_m1 = (const float*)d_in[15];
    const float* w_m2 = (const float*)d_in[16];
    const float* b_m2 = (const float*)d_in[17];
    const float* rel_h= (const float*)d_in[18];
    const float* rel_w= (const float*)d_in[19];
    const float* w_out= (const float*)d_in[20];
    const float* b_out= (const float*)d_in[21];
    float* out = (float*)d_out;

    float* ws   = (float*)d_ws;
    float* qs   = ws;
    float* ks   = qs + (size_t)Bc * 64 * HWc;
    float* vs   = ks + (size_t)Bc * 64 * HWc;
    float* t    = vs + (size_t)Bc * 64 * HWc;
    float* sa   = t  + (size_t)Bc * 17 * HWc;
    float* mpix = sa + (size_t)Bc * HWc;
    int*   flag = (int*)(mpix + (size_t)Bc * HWc);

    k_qkv  <<<576, 256, 0, stream>>>(x, wq, bq, wk, bk, wv, bv, qs, ks, vs);
    k_cond <<<576, 256, 0, stream>>>(vs, cg, w_in, b_in, ln_w, ln_b, t, mpix);
    k_sa   <<<576, 256, 0, stream>>>(t, w_sa, b_sa, sa);
    k_score<<<4, 576, 0, stream>>>(mpix, w_m1, b_m1, w_m2, b_m2, flag);
    k_attn <<<2304, 256, 0, stream>>>(qs, ks, vs, sa, flag, rel_h, rel_w, w_out, b_out, out);
}

// Round 2
// 607.211 us; speedup vs baseline: 1.5214x; 1.5214x over previous
//
#include <hip/hip_runtime.h>
#include <math.h>

#define Hh 192
#define Ww 192
#define HWc 36864
#define Bc 4
#define NWc 576
#define NKc 288
#define WNc 24

// ---- K1: q/k/v 1x1 convs (48 -> 3x64), output layout [b][y][x][c] ----
__global__ __launch_bounds__(256) void k_qkv(const float* __restrict__ x,
    const float* __restrict__ wq, const float* __restrict__ bq,
    const float* __restrict__ wk, const float* __restrict__ bk,
    const float* __restrict__ wv, const float* __restrict__ bv,
    float* __restrict__ q, float* __restrict__ k, float* __restrict__ v)
{
    int g = blockIdx.x * 256 + threadIdx.x;
    int b = g / HWc, rem = g % HWc;
    float xr[48];
    const float* xp = x + (size_t)b * 48 * HWc + rem;
    #pragma unroll
    for (int c = 0; c < 48; ++c) xr[c] = xp[(size_t)c * HWc];

    float* qp = q + (size_t)g * 64;
    #pragma unroll 1
    for (int o4 = 0; o4 < 16; ++o4) {
        float r[4];
        #pragma unroll
        for (int j = 0; j < 4; ++j) {
            int oc = o4 * 4 + j;
            float a = bq[oc];
            const float* wr = wq + oc * 48;
            #pragma unroll
            for (int c = 0; c < 48; ++c) a = fmaf(xr[c], wr[c], a);
            r[j] = a;
        }
        *(float4*)(qp + o4 * 4) = make_float4(r[0], r[1], r[2], r[3]);
    }
    float* kp = k + (size_t)g * 64;
    #pragma unroll 1
    for (int o4 = 0; o4 < 16; ++o4) {
        float r[4];
        #pragma unroll
        for (int j = 0; j < 4; ++j) {
            int oc = o4 * 4 + j;
            float a = bk[oc];
            const float* wr = wk + oc * 48;
            #pragma unroll
            for (int c = 0; c < 48; ++c) a = fmaf(xr[c], wr[c], a);
            r[j] = a;
        }
        *(float4*)(kp + o4 * 4) = make_float4(r[0], r[1], r[2], r[3]);
    }
    float* vp = v + (size_t)g * 64;
    #pragma unroll 1
    for (int o4 = 0; o4 < 16; ++o4) {
        float r[4];
        #pragma unroll
        for (int j = 0; j < 4; ++j) {
            int oc = o4 * 4 + j;
            float a = bv[oc];
            const float* wr = wv + oc * 48;
            #pragma unroll
            for (int c = 0; c < 48; ++c) a = fmaf(xr[c], wr[c], a);
            r[j] = a;
        }
        *(float4*)(vp + o4 * 4) = make_float4(r[0], r[1], r[2], r[3]);
    }
}

// ------- K2: cond conv (68->17) + LayerNorm + leaky + channel-mean -------
__global__ __launch_bounds__(256) void k_cond(const float* __restrict__ vs,
    const float* __restrict__ cg,
    const float* __restrict__ w_in, const float* __restrict__ b_in,
    const float* __restrict__ ln_w, const float* __restrict__ ln_b,
    float* __restrict__ t, float* __restrict__ mpix)
{
    int g = blockIdx.x * 256 + threadIdx.x;
    int b = g / HWc, rem = g % HWc;
    int y = rem / Ww, xx = rem % Ww;

    float in[68];
    const float* vp = vs + (size_t)g * 64;
    #pragma unroll
    for (int c = 0; c < 64; c += 4) {
        float4 t4 = *(const float4*)(vp + c);
        in[c] = t4.x; in[c+1] = t4.y; in[c+2] = t4.z; in[c+3] = t4.w;
    }
    in[64] = cg[((size_t)b * 2 + 0) * HWc + rem];
    in[65] = cg[((size_t)b * 2 + 1) * HWc + rem];
    const float step = 2.0f / 7.0f;
    in[66] = -1.0f + step * (float)(y & 7);
    in[67] = -1.0f + step * (float)(xx & 7);

    float tv[17];
    float mu = 0.f;
    #pragma unroll
    for (int o = 0; o < 17; ++o) {
        float a = b_in[o];
        const float* wr = w_in + o * 68;
        #pragma unroll
        for (int c = 0; c < 68; ++c) a = fmaf(in[c], wr[c], a);
        tv[o] = a;
        mu += a;
    }
    mu *= (1.f / 17.f);
    float var = 0.f;
    #pragma unroll
    for (int o = 0; o < 17; ++o) { float d = tv[o] - mu; var = fmaf(d, d, var); }
    var *= (1.f / 17.f);
    float rstd = 1.f / sqrtf(var + 1e-6f);

    float msum = 0.f;
    #pragma unroll
    for (int o = 0; o < 17; ++o) {
        float z = (tv[o] - mu) * rstd * ln_w[o] + ln_b[o];
        z = (z >= 0.f) ? z : 0.1f * z;
        t[((size_t)b * 17 + o) * HWc + rem] = z;
        msum += z;
    }
    mpix[(size_t)b * HWc + rem] = msum * (1.f / 17.f);
}

// ---------------- K3: 3x3 conv (17->1) + sigmoid ----------------
__global__ __launch_bounds__(256) void k_sa(const float* __restrict__ t,
    const float* __restrict__ w_sa, const float* __restrict__ b_sa,
    float* __restrict__ sa)
{
    int g = blockIdx.x * 256 + threadIdx.x;
    int b = g / HWc, rem = g % HWc;
    int y = rem / Ww, xx = rem % Ww;

    float a = b_sa[0];
    for (int c = 0; c < 17; ++c) {
        const float* tp = t + ((size_t)b * 17 + c) * HWc;
        const float* wr = w_sa + c * 9;
        #pragma unroll
        for (int ki = 0; ki < 3; ++ki) {
            int yy = y + ki - 1;
            if ((unsigned)yy >= 192u) continue;
            #pragma unroll
            for (int kj = 0; kj < 3; ++kj) {
                int xc = xx + kj - 1;
                if ((unsigned)xc >= 192u) continue;
                a = fmaf(tp[yy * Ww + xc], wr[ki * 3 + kj], a);
            }
        }
    }
    sa[g] = 1.f / (1.f + expf(-a));
}

// -------- K4: window score MLP + stable descending rank -> flag --------
__global__ __launch_bounds__(576) void k_score(const float* __restrict__ mpix,
    const float* __restrict__ w_m1, const float* __restrict__ b_m1,
    const float* __restrict__ w_m2, const float* __restrict__ b_m2,
    int* __restrict__ flag)
{
    __shared__ float sc[NWc];
    int b = blockIdx.x;
    int w = threadIdx.x;
    {
        int hy = w / WNc, wx = w % WNc;
        const float* mp = mpix + (size_t)b * HWc + (hy * 8) * Ww + wx * 8;
        float m[64];
        #pragma unroll
        for (int l = 0; l < 64; ++l) m[l] = mp[(l >> 3) * Ww + (l & 7)];
        float h1[8];
        #pragma unroll
        for (int j = 0; j < 8; ++j) {
            float a = b_m1[j];
            const float* wr = w_m1 + j * 64;
            #pragma unroll
            for (int l = 0; l < 64; ++l) a = fmaf(m[l], wr[l], a);
            h1[j] = (a >= 0.f) ? a : 0.1f * a;
        }
        float l0 = b_m2[0], l1 = b_m2[1];
        #pragma unroll
        for (int j = 0; j < 8; ++j) {
            l0 = fmaf(h1[j], w_m2[j], l0);
            l1 = fmaf(h1[j], w_m2[8 + j], l1);
        }
        float mx = fmaxf(l0, l1);
        float e0 = expf(l0 - mx), e1 = expf(l1 - mx);
        sc[w] = e0 / (e0 + e1);
    }
    __syncthreads();
    float s = sc[w];
    int cnt = 0;
    for (int w2 = 0; w2 < NWc; ++w2) {
        float s2 = sc[w2];
        cnt += ((s2 > s) || (s2 == s && w2 < w)) ? 1 : 0;
    }
    flag[b * NWc + w] = (cnt < NKc) ? 1 : 0;
}

// ---- K5: per-window attention OR easy path + fused output 1x1 conv ----
__global__ __launch_bounds__(256) void k_attn(const float* __restrict__ qs,
    const float* __restrict__ ks, const float* __restrict__ vsb,
    const float* __restrict__ sab, const int* __restrict__ flag,
    const float* __restrict__ relh, const float* __restrict__ relw,
    const float* __restrict__ w_out, const float* __restrict__ b_out,
    float* __restrict__ out)
{
    __shared__ float mlds[64][65];     // [pixel][channel], +1 pad
    __shared__ float wlds[48 * 64];    // w_out staged
    int tid = threadIdx.x;
    for (int i = tid; i < 48 * 64; i += 256) wlds[i] = w_out[i];

    int blk = blockIdx.x;
    int b = blk / NWc, n = blk % NWc;
    int hy = n / WNc, wx = n % WNc;
    int y0 = hy * 8, x0 = wx * 8;

    if (flag[b * NWc + n]) {
        int h = __builtin_amdgcn_readfirstlane(tid >> 6);  // head, wave-uniform SGPR
        int l = tid & 63;
        int qr = l >> 3, qc = l & 7;

        const float* qp = qs + ((size_t)(b * HWc) + (y0 + qr) * Ww + (x0 + qc)) * 64 + h * 16;
        float qv[16];
        #pragma unroll
        for (int j = 0; j < 4; ++j) {
            float4 t4 = *(const float4*)(qp + j * 4);
            qv[j*4+0] = t4.x; qv[j*4+1] = t4.y; qv[j*4+2] = t4.z; qv[j*4+3] = t4.w;
        }

        // relative-position logit tables (rel index in [4,22], always valid)
        float rw[12], rh[12];
        #pragma unroll
        for (int kc = 0; kc < 12; ++kc) {
            const float* rp = relw + (kc - qc + 11) * 16;
            float a = 0.f;
            #pragma unroll
            for (int j = 0; j < 4; ++j) {
                float4 t4 = *(const float4*)(rp + j * 4);
                a = fmaf(qv[j*4+0], t4.x, a); a = fmaf(qv[j*4+1], t4.y, a);
                a = fmaf(qv[j*4+2], t4.z, a); a = fmaf(qv[j*4+3], t4.w, a);
            }
            rw[kc] = a;
        }
        #pragma unroll
        for (int kr = 0; kr < 12; ++kr) {
            const float* rp = relh + (kr - qr + 11) * 16;
            float a = 0.f;
            #pragma unroll
            for (int j = 0; j < 4; ++j) {
                float4 t4 = *(const float4*)(rp + j * 4);
                a = fmaf(qv[j*4+0], t4.x, a); a = fmaf(qv[j*4+1], t4.y, a);
                a = fmaf(qv[j*4+2], t4.z, a); a = fmaf(qv[j*4+3], t4.w, a);
            }
            rh[kr] = a;
        }

        // cheap shift (upper bound of rel part) -> exp arg bounded, softmax invariant
        float mw = rw[0], mh = rh[0];
        #pragma unroll
        for (int i = 1; i < 12; ++i) { mw = fmaxf(mw, rw[i]); mh = fmaxf(mh, rh[i]); }
        float mrel = mw + mh;

        const float* kb = ks  + (size_t)(b * HWc) * 64 + h * 16;
        const float* vb = vsb + (size_t)(b * HWc) * 64 + h * 16;

        float lsum = 0.f;
        float acc[16];
        #pragma unroll
        for (int d = 0; d < 16; ++d) acc[d] = 0.f;

        #pragma unroll 1
        for (int kr = 0; kr < 12; ++kr) {
            int ky = y0 - 2 + kr;
            bool rok = ((unsigned)ky < 192u);
            const float* krow = kb + ((size_t)ky * Ww + (x0 - 2)) * 64;
            const float* vrow = vb + ((size_t)ky * Ww + (x0 - 2)) * 64;
            #pragma unroll 4
            for (int kc = 0; kc < 12; ++kc) {
                int kx = x0 - 2 + kc;
                bool inb = rok && ((unsigned)kx < 192u);   // block-uniform
                float s = rw[kc] + rh[kr] - mrel;
                if (inb) {
                    const float* kp = krow + kc * 64;
                    float dt = 0.f;
                    #pragma unroll
                    for (int j = 0; j < 4; ++j) {
                        float4 k4 = *(const float4*)(kp + j * 4);
                        dt = fmaf(qv[j*4+0], k4.x, dt); dt = fmaf(qv[j*4+1], k4.y, dt);
                        dt = fmaf(qv[j*4+2], k4.z, dt); dt = fmaf(qv[j*4+3], k4.w, dt);
                    }
                    s = fmaf(0.25f, dt, s);
                }
                float e = __expf(s);
                lsum += e;
                if (inb) {
                    const float* vp = vrow + kc * 64;
                    #pragma unroll
                    for (int j = 0; j < 4; ++j) {
                        float4 v4 = *(const float4*)(vp + j * 4);
                        acc[j*4+0] = fmaf(e, v4.x, acc[j*4+0]);
                        acc[j*4+1] = fmaf(e, v4.y, acc[j*4+1]);
                        acc[j*4+2] = fmaf(e, v4.z, acc[j*4+2]);
                        acc[j*4+3] = fmaf(e, v4.w, acc[j*4+3]);
                    }
                }
            }
        }
        float inv = 1.f / lsum;
        #pragma unroll
        for (int d = 0; d < 16; ++d) mlds[l][h * 16 + d] = acc[d] * inv;
    } else {
        // easy path: vs * sa
        int l = tid >> 2, part = tid & 3;
        int gy = y0 + (l >> 3), gx = x0 + (l & 7);
        const float* vp = vsb + ((size_t)(b * HWc) + gy * Ww + gx) * 64 + part * 16;
        float sv = sab[(size_t)b * HWc + gy * Ww + gx];
        #pragma unroll
        for (int j = 0; j < 4; ++j) {
            float4 v4 = *(const float4*)(vp + j * 4);
            mlds[l][part*16 + j*4 + 0] = v4.x * sv;
            mlds[l][part*16 + j*4 + 1] = v4.y * sv;
            mlds[l][part*16 + j*4 + 2] = v4.z * sv;
            mlds[l][part*16 + j*4 + 3] = v4.w * sv;
        }
    }
    __syncthreads();

    // fused output conv: 64 -> 48 per pixel
    {
        int l = tid & 63, og = tid >> 6;
        int gy = y0 + (l >> 3), gx = x0 + (l & 7);
        float mv[64];
        #pragma unroll
        for (int c = 0; c < 64; ++c) mv[c] = mlds[l][c];
        #pragma unroll 1
        for (int j = 0; j < 12; ++j) {
            int oc = og * 12 + j;
            float a = b_out[oc];
            const float* wr = wlds + oc * 64;
            #pragma unroll
            for (int c = 0; c < 64; ++c) a = fmaf(mv[c], wr[c], a);
            out[((size_t)(b * 48 + oc)) * HWc + gy * Ww + gx] = a;
        }
    }
}

extern "C" void kernel_launch(void* const* d_in, const int* in_sizes, int n_in,
                              void* d_out, int out_size, void* d_ws, size_t ws_size,
                              hipStream_t stream)
{
    const float* x    = (const float*)d_in[0];
    const float* cg   = (const float*)d_in[1];
    const float* wq   = (const float*)d_in[2];
    const float* bq   = (const float*)d_in[3];
    const float* wk   = (const float*)d_in[4];
    const float* bk   = (const float*)d_in[5];
    const float* wv   = (const float*)d_in[6];
    const float* bv   = (const float*)d_in[7];
    const float* w_in = (const float*)d_in[8];
    const float* b_in = (const float*)d_in[9];
    const float* ln_w = (const float*)d_in[10];
    const float* ln_b = (const float*)d_in[11];
    const float* w_sa = (const float*)d_in[12];
    const float* b_sa = (const float*)d_in[13];
    const float* w_m1 = (const float*)d_in[14];
    const float* b_m1 = (const float*)d_in[15];
    const float* w_m2 = (const float*)d_in[16];
    const float* b_m2 = (const float*)d_in[17];
    const float* rel_h= (const float*)d_in[18];
    const float* rel_w= (const float*)d_in[19];
    const float* w_out= (const float*)d_in[20];
    const float* b_out= (const float*)d_in[21];
    float* out = (float*)d_out;

    float* ws   = (float*)d_ws;
    float* qs   = ws;
    float* ks   = qs + (size_t)Bc * 64 * HWc;
    float* vs   = ks + (size_t)Bc * 64 * HWc;
    float* t    = vs + (size_t)Bc * 64 * HWc;
    float* sa   = t  + (size_t)Bc * 17 * HWc;
    float* mpix = sa + (size_t)Bc * HWc;
    int*   flag = (int*)(mpix + (size_t)Bc * HWc);

    k_qkv  <<<576, 256, 0, stream>>>(x, wq, bq, wk, bk, wv, bv, qs, ks, vs);
    k_cond <<<576, 256, 0, stream>>>(vs, cg, w_in, b_in, ln_w, ln_b, t, mpix);
    k_sa   <<<576, 256, 0, stream>>>(t, w_sa, b_sa, sa);
    k_score<<<4, 576, 0, stream>>>(mpix, w_m1, b_m1, w_m2, b_m2, flag);
    k_attn <<<2304, 256, 0, stream>>>(qs, ks, vs, sa, flag, rel_h, rel_w, w_out, b_out, out);
}

// Round 3
// 418.520 us; speedup vs baseline: 2.2074x; 1.4509x over previous
//
#include <hip/hip_runtime.h>
#include <math.h>

#define Hh 192
#define Ww 192
#define HWc 36864
#define Bc 4
#define NWc 576
#define NKc 288
#define WNc 24

// ---- K1: q/k/v 1x1 convs (48 -> 3x64), output layout [b][y][x][c] ----
__global__ __launch_bounds__(256) void k_qkv(const float* __restrict__ x,
    const float* __restrict__ wq, const float* __restrict__ bq,
    const float* __restrict__ wk, const float* __restrict__ bk,
    const float* __restrict__ wv, const float* __restrict__ bv,
    float* __restrict__ q, float* __restrict__ k, float* __restrict__ v)
{
    int g = blockIdx.x * 256 + threadIdx.x;
    int b = g / HWc, rem = g % HWc;
    float xr[48];
    const float* xp = x + (size_t)b * 48 * HWc + rem;
    #pragma unroll
    for (int c = 0; c < 48; ++c) xr[c] = xp[(size_t)c * HWc];

    float* qp = q + (size_t)g * 64;
    #pragma unroll 1
    for (int o4 = 0; o4 < 16; ++o4) {
        float r[4];
        #pragma unroll
        for (int j = 0; j < 4; ++j) {
            int oc = o4 * 4 + j;
            float a = bq[oc];
            const float* wr = wq + oc * 48;
            #pragma unroll
            for (int c = 0; c < 48; ++c) a = fmaf(xr[c], wr[c], a);
            r[j] = a;
        }
        *(float4*)(qp + o4 * 4) = make_float4(r[0], r[1], r[2], r[3]);
    }
    float* kp = k + (size_t)g * 64;
    #pragma unroll 1
    for (int o4 = 0; o4 < 16; ++o4) {
        float r[4];
        #pragma unroll
        for (int j = 0; j < 4; ++j) {
            int oc = o4 * 4 + j;
            float a = bk[oc];
            const float* wr = wk + oc * 48;
            #pragma unroll
            for (int c = 0; c < 48; ++c) a = fmaf(xr[c], wr[c], a);
            r[j] = a;
        }
        *(float4*)(kp + o4 * 4) = make_float4(r[0], r[1], r[2], r[3]);
    }
    float* vp = v + (size_t)g * 64;
    #pragma unroll 1
    for (int o4 = 0; o4 < 16; ++o4) {
        float r[4];
        #pragma unroll
        for (int j = 0; j < 4; ++j) {
            int oc = o4 * 4 + j;
            float a = bv[oc];
            const float* wr = wv + oc * 48;
            #pragma unroll
            for (int c = 0; c < 48; ++c) a = fmaf(xr[c], wr[c], a);
            r[j] = a;
        }
        *(float4*)(vp + o4 * 4) = make_float4(r[0], r[1], r[2], r[3]);
    }
}

// ------- K2: cond conv (68->17) + LayerNorm + leaky + channel-mean -------
__global__ __launch_bounds__(256) void k_cond(const float* __restrict__ vs,
    const float* __restrict__ cg,
    const float* __restrict__ w_in, const float* __restrict__ b_in,
    const float* __restrict__ ln_w, const float* __restrict__ ln_b,
    float* __restrict__ t, float* __restrict__ mpix)
{
    int g = blockIdx.x * 256 + threadIdx.x;
    int b = g / HWc, rem = g % HWc;
    int y = rem / Ww, xx = rem % Ww;

    float in[68];
    const float* vp = vs + (size_t)g * 64;
    #pragma unroll
    for (int c = 0; c < 64; c += 4) {
        float4 t4 = *(const float4*)(vp + c);
        in[c] = t4.x; in[c+1] = t4.y; in[c+2] = t4.z; in[c+3] = t4.w;
    }
    in[64] = cg[((size_t)b * 2 + 0) * HWc + rem];
    in[65] = cg[((size_t)b * 2 + 1) * HWc + rem];
    const float step = 2.0f / 7.0f;
    in[66] = -1.0f + step * (float)(y & 7);
    in[67] = -1.0f + step * (float)(xx & 7);

    float tv[17];
    float mu = 0.f;
    #pragma unroll
    for (int o = 0; o < 17; ++o) {
        float a = b_in[o];
        const float* wr = w_in + o * 68;
        #pragma unroll
        for (int c = 0; c < 68; ++c) a = fmaf(in[c], wr[c], a);
        tv[o] = a;
        mu += a;
    }
    mu *= (1.f / 17.f);
    float var = 0.f;
    #pragma unroll
    for (int o = 0; o < 17; ++o) { float d = tv[o] - mu; var = fmaf(d, d, var); }
    var *= (1.f / 17.f);
    float rstd = 1.f / sqrtf(var + 1e-6f);

    float msum = 0.f;
    #pragma unroll
    for (int o = 0; o < 17; ++o) {
        float z = (tv[o] - mu) * rstd * ln_w[o] + ln_b[o];
        z = (z >= 0.f) ? z : 0.1f * z;
        t[((size_t)b * 17 + o) * HWc + rem] = z;
        msum += z;
    }
    mpix[(size_t)b * HWc + rem] = msum * (1.f / 17.f);
}

// ---------------- K3: 3x3 conv (17->1) + sigmoid ----------------
__global__ __launch_bounds__(256) void k_sa(const float* __restrict__ t,
    const float* __restrict__ w_sa, const float* __restrict__ b_sa,
    float* __restrict__ sa)
{
    int g = blockIdx.x * 256 + threadIdx.x;
    int b = g / HWc, rem = g % HWc;
    int y = rem / Ww, xx = rem % Ww;

    float a = b_sa[0];
    for (int c = 0; c < 17; ++c) {
        const float* tp = t + ((size_t)b * 17 + c) * HWc;
        const float* wr = w_sa + c * 9;
        #pragma unroll
        for (int ki = 0; ki < 3; ++ki) {
            int yy = y + ki - 1;
            if ((unsigned)yy >= 192u) continue;
            #pragma unroll
            for (int kj = 0; kj < 3; ++kj) {
                int xc = xx + kj - 1;
                if ((unsigned)xc >= 192u) continue;
                a = fmaf(tp[yy * Ww + xc], wr[ki * 3 + kj], a);
            }
        }
    }
    sa[g] = 1.f / (1.f + expf(-a));
}

// -------- K4: window score MLP + stable descending rank -> flag --------
__global__ __launch_bounds__(576) void k_score(const float* __restrict__ mpix,
    const float* __restrict__ w_m1, const float* __restrict__ b_m1,
    const float* __restrict__ w_m2, const float* __restrict__ b_m2,
    int* __restrict__ flag)
{
    __shared__ float sc[NWc];
    int b = blockIdx.x;
    int w = threadIdx.x;
    {
        int hy = w / WNc, wx = w % WNc;
        const float* mp = mpix + (size_t)b * HWc + (hy * 8) * Ww + wx * 8;
        float m[64];
        #pragma unroll
        for (int l = 0; l < 64; ++l) m[l] = mp[(l >> 3) * Ww + (l & 7)];
        float h1[8];
        #pragma unroll
        for (int j = 0; j < 8; ++j) {
            float a = b_m1[j];
            const float* wr = w_m1 + j * 64;
            #pragma unroll
            for (int l = 0; l < 64; ++l) a = fmaf(m[l], wr[l], a);
            h1[j] = (a >= 0.f) ? a : 0.1f * a;
        }
        float l0 = b_m2[0], l1 = b_m2[1];
        #pragma unroll
        for (int j = 0; j < 8; ++j) {
            l0 = fmaf(h1[j], w_m2[j], l0);
            l1 = fmaf(h1[j], w_m2[8 + j], l1);
        }
        float mx = fmaxf(l0, l1);
        float e0 = expf(l0 - mx), e1 = expf(l1 - mx);
        sc[w] = e0 / (e0 + e1);
    }
    __syncthreads();
    float s = sc[w];
    int cnt = 0;
    for (int w2 = 0; w2 < NWc; ++w2) {
        float s2 = sc[w2];
        cnt += ((s2 > s) || (s2 == s && w2 < w)) ? 1 : 0;
    }
    flag[b * NWc + w] = (cnt < NKc) ? 1 : 0;
}

// ---- K5: per-window attention (LDS-staged K/V) + fused output conv ----
__global__ __launch_bounds__(256) void k_attn(const float* __restrict__ qs,
    const float* __restrict__ ks, const float* __restrict__ vsb,
    const float* __restrict__ sab, const int* __restrict__ flag,
    const float* __restrict__ relh, const float* __restrict__ relw,
    const float* __restrict__ w_out, const float* __restrict__ b_out,
    float* __restrict__ out)
{
    __shared__ float kbuf[144 * 64];   // 36864 B; aliased as mlds[64][65] later
    __shared__ float vbuf[144 * 64];   // 36864 B
    float (*mlds)[65] = (float (*)[65])kbuf;

    int tid = threadIdx.x;
    int blk = blockIdx.x;
    int b = blk / NWc, n = blk % NWc;
    int hy = n / WNc, wx = n % WNc;
    int y0 = hy * 8, x0 = wx * 8;

    if (flag[b * NWc + n]) {
        // ---- cooperative stage of 12x12x64 K and V patches, zero-filled OOB ----
        #pragma unroll
        for (int i = 0; i < 9; ++i) {
            int idx = i * 256 + tid;          // 0..2303 = 144 px * 16 chunks
            int px = idx >> 4, c4 = idx & 15;
            int py = px / 12, pxx = px - py * 12;
            int ky = y0 - 2 + py, kx = x0 - 2 + pxx;
            bool ok = ((unsigned)ky < 192u) && ((unsigned)kx < 192u);
            int kyc = min(max(ky, 0), 191), kxc = min(max(kx, 0), 191);
            size_t goff = ((size_t)(b * HWc) + kyc * Ww + kxc) * 64 + c4 * 4;
            float4 k4 = *(const float4*)(ks + goff);
            float4 v4 = *(const float4*)(vsb + goff);
            if (!ok) { k4 = make_float4(0,0,0,0); v4 = make_float4(0,0,0,0); }
            *(float4*)(kbuf + px * 64 + c4 * 4) = k4;
            *(float4*)(vbuf + px * 64 + c4 * 4) = v4;
        }
        __syncthreads();

        int h = __builtin_amdgcn_readfirstlane(tid >> 6);  // head, SGPR
        int l = tid & 63;
        int qr = l >> 3, qc = l & 7;

        const float* qp = qs + ((size_t)(b * HWc) + (y0 + qr) * Ww + (x0 + qc)) * 64 + h * 16;
        float qv[16];
        #pragma unroll
        for (int j = 0; j < 4; ++j) {
            float4 t4 = *(const float4*)(qp + j * 4);
            qv[j*4+0] = t4.x; qv[j*4+1] = t4.y; qv[j*4+2] = t4.z; qv[j*4+3] = t4.w;
        }

        // relative-position logit tables (rel index in [4,22], always valid)
        float rw[12], rh[12];
        #pragma unroll
        for (int kc = 0; kc < 12; ++kc) {
            const float* rp = relw + (kc - qc + 11) * 16;
            float a = 0.f;
            #pragma unroll
            for (int j = 0; j < 4; ++j) {
                float4 t4 = *(const float4*)(rp + j * 4);
                a = fmaf(qv[j*4+0], t4.x, a); a = fmaf(qv[j*4+1], t4.y, a);
                a = fmaf(qv[j*4+2], t4.z, a); a = fmaf(qv[j*4+3], t4.w, a);
            }
            rw[kc] = a;
        }
        #pragma unroll
        for (int kr = 0; kr < 12; ++kr) {
            const float* rp = relh + (kr - qr + 11) * 16;
            float a = 0.f;
            #pragma unroll
            for (int j = 0; j < 4; ++j) {
                float4 t4 = *(const float4*)(rp + j * 4);
                a = fmaf(qv[j*4+0], t4.x, a); a = fmaf(qv[j*4+1], t4.y, a);
                a = fmaf(qv[j*4+2], t4.z, a); a = fmaf(qv[j*4+3], t4.w, a);
            }
            rh[kr] = a;
        }

        // cheap shift (upper bound of rel part) -> exp arg bounded, softmax invariant
        float mw = rw[0], mh = rh[0];
        #pragma unroll
        for (int i = 1; i < 12; ++i) { mw = fmaxf(mw, rw[i]); mh = fmaxf(mh, rh[i]); }
        float mrel = mw + mh;

        float lsum = 0.f;
        float acc[16];
        #pragma unroll
        for (int d = 0; d < 16; ++d) acc[d] = 0.f;

        // ---- branchless 144-key loop, K/V from LDS (broadcast reads) ----
        #pragma unroll 1
        for (int kr = 0; kr < 12; ++kr) {
            float rhv = rh[kr];
            const float* kRow = kbuf + (kr * 12) * 64 + h * 16;
            const float* vRow = vbuf + (kr * 12) * 64 + h * 16;
            #pragma unroll 4
            for (int kc = 0; kc < 12; ++kc) {
                const float* kp = kRow + kc * 64;
                float dt = 0.f;
                #pragma unroll
                for (int j = 0; j < 4; ++j) {
                    float4 k4 = *(const float4*)(kp + j * 4);
                    dt = fmaf(qv[j*4+0], k4.x, dt); dt = fmaf(qv[j*4+1], k4.y, dt);
                    dt = fmaf(qv[j*4+2], k4.z, dt); dt = fmaf(qv[j*4+3], k4.w, dt);
                }
                float s = rw[kc] + rhv - mrel + 0.25f * dt;
                float e = __expf(s);
                lsum += e;
                const float* vp2 = vRow + kc * 64;
                #pragma unroll
                for (int j = 0; j < 4; ++j) {
                    float4 v4 = *(const float4*)(vp2 + j * 4);
                    acc[j*4+0] = fmaf(e, v4.x, acc[j*4+0]);
                    acc[j*4+1] = fmaf(e, v4.y, acc[j*4+1]);
                    acc[j*4+2] = fmaf(e, v4.z, acc[j*4+2]);
                    acc[j*4+3] = fmaf(e, v4.w, acc[j*4+3]);
                }
            }
        }
        __syncthreads();   // everyone done reading kbuf before aliased mlds write
        float inv = 1.f / lsum;
        #pragma unroll
        for (int d = 0; d < 16; ++d) mlds[l][h * 16 + d] = acc[d] * inv;
    } else {
        // easy path: vs * sa
        int l = tid >> 2, part = tid & 3;
        int gy = y0 + (l >> 3), gx = x0 + (l & 7);
        const float* vp = vsb + ((size_t)(b * HWc) + gy * Ww + gx) * 64 + part * 16;
        float sv = sab[(size_t)b * HWc + gy * Ww + gx];
        #pragma unroll
        for (int j = 0; j < 4; ++j) {
            float4 v4 = *(const float4*)(vp + j * 4);
            mlds[l][part*16 + j*4 + 0] = v4.x * sv;
            mlds[l][part*16 + j*4 + 1] = v4.y * sv;
            mlds[l][part*16 + j*4 + 2] = v4.z * sv;
            mlds[l][part*16 + j*4 + 3] = v4.w * sv;
        }
    }
    __syncthreads();

    // fused output conv: 64 -> 48 per pixel (weights via wave-uniform s_loads)
    {
        int l = tid & 63;
        int og = __builtin_amdgcn_readfirstlane(tid >> 6);
        int gy = y0 + (l >> 3), gx = x0 + (l & 7);
        float mv[64];
        #pragma unroll
        for (int c = 0; c < 64; ++c) mv[c] = mlds[l][c];
        #pragma unroll 1
        for (int j = 0; j < 12; ++j) {
            int oc = og * 12 + j;
            float a = b_out[oc];
            const float* wr = w_out + oc * 64;
            #pragma unroll
            for (int c = 0; c < 64; ++c) a = fmaf(mv[c], wr[c], a);
            out[((size_t)(b * 48 + oc)) * HWc + gy * Ww + gx] = a;
        }
    }
}

extern "C" void kernel_launch(void* const* d_in, const int* in_sizes, int n_in,
                              void* d_out, int out_size, void* d_ws, size_t ws_size,
                              hipStream_t stream)
{
    const float* x    = (const float*)d_in[0];
    const float* cg   = (const float*)d_in[1];
    const float* wq   = (const float*)d_in[2];
    const float* bq   = (const float*)d_in[3];
    const float* wk   = (const float*)d_in[4];
    const float* bk   = (const float*)d_in[5];
    const float* wv   = (const float*)d_in[6];
    const float* bv   = (const float*)d_in[7];
    const float* w_in = (const float*)d_in[8];
    const float* b_in = (const float*)d_in[9];
    const float* ln_w = (const float*)d_in[10];
    const float* ln_b = (const float*)d_in[11];
    const float* w_sa = (const float*)d_in[12];
    const float* b_sa = (const float*)d_in[13];
    const float* w_m1 = (const float*)d_in[14];
    const float* b_m1 = (const float*)d_in[15];
    const float* w_m2 = (const float*)d_in[16];
    const float* b_m2 = (const float*)d_in[17];
    const float* rel_h= (const float*)d_in[18];
    const float* rel_w= (const float*)d_in[19];
    const float* w_out= (const float*)d_in[20];
    const float* b_out= (const float*)d_in[21];
    float* out = (float*)d_out;

    float* ws   = (float*)d_ws;
    float* qs   = ws;
    float* ks   = qs + (size_t)Bc * 64 * HWc;
    float* vs   = ks + (size_t)Bc * 64 * HWc;
    float* t    = vs + (size_t)Bc * 64 * HWc;
    float* sa   = t  + (size_t)Bc * 17 * HWc;
    float* mpix = sa + (size_t)Bc * HWc;
    int*   flag = (int*)(mpix + (size_t)Bc * HWc);

    k_qkv  <<<576, 256, 0, stream>>>(x, wq, bq, wk, bk, wv, bv, qs, ks, vs);
    k_cond <<<576, 256, 0, stream>>>(vs, cg, w_in, b_in, ln_w, ln_b, t, mpix);
    k_sa   <<<576, 256, 0, stream>>>(t, w_sa, b_sa, sa);
    k_score<<<4, 576, 0, stream>>>(mpix, w_m1, b_m1, w_m2, b_m2, flag);
    k_attn <<<2304, 256, 0, stream>>>(qs, ks, vs, sa, flag, rel_h, rel_w, w_out, b_out, out);
}